// Round 1
// baseline (249.831 us; speedup 1.0000x reference)
//
#include <hip/hip_runtime.h>
#include <hip/hip_bf16.h>

// InstanceAttentionModule: B=32, H=W=32 (HW=1024), C=256, F=64, K_NEIGH=32.
// Pipeline:
//   k_emb      : emb = x@embW^T + b  (bf16 MFMA), store emb bf16 + sq (fp32, from rounded emb)
//   k_shortcut : shortcut = x@attnW^T + b (bf16 MFMA), store TRANSPOSED bf16 [b][c][j] + Tinst
//   k_scores   : per batch gram=emb@emb^T (MFMA), E=exp(exp(-d2)-1+mask) bf16, R=rowsum(E)
//   k_z        : Z_i = sum_j exp(max(E_ij/R_i - T_j, 0))
//   k_out      : out = x + A @ shortcut, A_ij = exp(max(E_ij/R_i - T_j,0))/Z_i (bf16 MFMA,
//                A-fragments computed in registers)

typedef short bf16x8 __attribute__((ext_vector_type(8)));
typedef float f32x4 __attribute__((ext_vector_type(4)));

__device__ __forceinline__ unsigned short f2bf(float f) {
  unsigned u = __float_as_uint(f);
  u += 0x7fffu + ((u >> 16) & 1u);   // round-to-nearest-even
  return (unsigned short)(u >> 16);
}
__device__ __forceinline__ float bf2f(unsigned short h) {
  return __uint_as_float(((unsigned)h) << 16);
}
__device__ __forceinline__ unsigned pack2(float a, float b) {
  return (unsigned)f2bf(a) | ((unsigned)f2bf(b) << 16);
}
__device__ __forceinline__ f32x4 mfma16(bf16x8 a, bf16x8 b, f32x4 c) {
  return __builtin_amdgcn_mfma_f32_16x16x32_bf16(a, b, c, 0, 0, 0);
}
__device__ __forceinline__ int iabs(int v) { return v < 0 ? -v : v; }

// ---------------------------------------------------------------- k_emb
// grid 512, block 256. M-tile 64 rows x N=64 (full F). waves 2x2 (32x32 each).
__global__ __launch_bounds__(256) void k_emb(const float* __restrict__ x,
                                             const float* __restrict__ embW,
                                             const float* __restrict__ embB,
                                             unsigned short* __restrict__ embb,
                                             float* __restrict__ sq) {
  __shared__ unsigned short xs[64][40];
  __shared__ unsigned short ws[64][40];
  __shared__ float sqls[64];
  const int t = threadIdx.x;
  const int Mbase = blockIdx.x * 64;
  const int lane = t & 63, wave = t >> 6;
  const int wm = wave >> 1, wn = wave & 1;
  const int l15 = lane & 15, quad = lane >> 4;

  f32x4 acc[2][2] = {};
  for (int k0 = 0; k0 < 256; k0 += 32) {
    { // stage x tile -> bf16 LDS
      int row = t >> 2, c0 = (t & 3) * 8;
      const float* src = x + (size_t)(Mbase + row) * 256 + k0 + c0;
      float4 a = *(const float4*)src;
      float4 b = *(const float4*)(src + 4);
      uint4 p; p.x = pack2(a.x, a.y); p.y = pack2(a.z, a.w);
      p.z = pack2(b.x, b.y); p.w = pack2(b.z, b.w);
      *(uint4*)&xs[row][c0] = p;
    }
    if (t < 64) { // stage weight tile
      const float* wsrc = embW + (size_t)t * 256 + k0;
      for (int s = 0; s < 4; s++) {
        float4 a = *(const float4*)(wsrc + s * 8);
        float4 b = *(const float4*)(wsrc + s * 8 + 4);
        uint4 p; p.x = pack2(a.x, a.y); p.y = pack2(a.z, a.w);
        p.z = pack2(b.x, b.y); p.w = pack2(b.z, b.w);
        *(uint4*)&ws[t][s * 8] = p;
      }
    }
    __syncthreads();
    bf16x8 af[2], bfr[2];
    for (int rt = 0; rt < 2; rt++)
      af[rt] = *(const bf16x8*)&xs[wm * 32 + rt * 16 + l15][quad * 8];
    for (int ct = 0; ct < 2; ct++)
      bfr[ct] = *(const bf16x8*)&ws[wn * 32 + ct * 16 + l15][quad * 8];
    for (int rt = 0; rt < 2; rt++)
      for (int ct = 0; ct < 2; ct++)
        acc[rt][ct] = mfma16(af[rt], bfr[ct], acc[rt][ct]);
    __syncthreads();
  }

  if (t < 64) sqls[t] = 0.f;
  __syncthreads();
  float sp[2][4] = {};
  for (int rt = 0; rt < 2; rt++)
    for (int ct = 0; ct < 2; ct++) {
      int f = wn * 32 + ct * 16 + l15;
      float bias = embB[f];
      for (int r = 0; r < 4; r++) {
        float v = acc[rt][ct][r] + bias;
        unsigned short hb = f2bf(v);
        int rowl = wm * 32 + rt * 16 + quad * 4 + r;
        embb[(size_t)(Mbase + rowl) * 64 + f] = hb;
        float vf = bf2f(hb);
        sp[rt][r] += vf * vf;  // sq from ROUNDED emb (consistency with gram)
      }
    }
  for (int m = 8; m >= 1; m >>= 1)
    for (int rt = 0; rt < 2; rt++)
      for (int r = 0; r < 4; r++)
        sp[rt][r] += __shfl_xor(sp[rt][r], m);
  if (l15 == 0)
    for (int rt = 0; rt < 2; rt++)
      for (int r = 0; r < 4; r++)
        atomicAdd(&sqls[wm * 32 + rt * 16 + quad * 4 + r], sp[rt][r]);
  __syncthreads();
  if (t < 64) sq[Mbase + t] = sqls[t];
}

// ---------------------------------------------------------------- k_shortcut
// grid 512, block 256. M-tile 64 x N=256 full. waves 2x2 (32 rows x 128 cols).
__global__ __launch_bounds__(256) void k_shortcut(const float* __restrict__ x,
                                                  const float* __restrict__ attnW,
                                                  const float* __restrict__ attnB,
                                                  const float* __restrict__ thrW,
                                                  const float* __restrict__ thrB,
                                                  unsigned short* __restrict__ scT,
                                                  float* __restrict__ Tout) {
  __shared__ unsigned short xs[64][40];
  __shared__ unsigned short ws[256][40];
  __shared__ unsigned short St[256][72];   // [c][j], padded (72*2=144B rows, 16B-aligned)
  const int t = threadIdx.x;
  const int Mbase = blockIdx.x * 64;
  const int lane = t & 63, wave = t >> 6;
  const int wm = wave >> 1, wn = wave & 1;
  const int l15 = lane & 15, quad = lane >> 4;

  f32x4 acc[2][8] = {};
  for (int k0 = 0; k0 < 256; k0 += 32) {
    {
      int row = t >> 2, c0 = (t & 3) * 8;
      const float* src = x + (size_t)(Mbase + row) * 256 + k0 + c0;
      float4 a = *(const float4*)src;
      float4 b = *(const float4*)(src + 4);
      uint4 p; p.x = pack2(a.x, a.y); p.y = pack2(a.z, a.w);
      p.z = pack2(b.x, b.y); p.w = pack2(b.z, b.w);
      *(uint4*)&xs[row][c0] = p;
    }
    { // stage attn_W tile: thread t handles output-channel row t
      const float* wsrc = attnW + (size_t)t * 256 + k0;
      for (int s = 0; s < 4; s++) {
        float4 a = *(const float4*)(wsrc + s * 8);
        float4 b = *(const float4*)(wsrc + s * 8 + 4);
        uint4 p; p.x = pack2(a.x, a.y); p.y = pack2(a.z, a.w);
        p.z = pack2(b.x, b.y); p.w = pack2(b.z, b.w);
        *(uint4*)&ws[t][s * 8] = p;
      }
    }
    __syncthreads();
    bf16x8 af[2];
    for (int rt = 0; rt < 2; rt++)
      af[rt] = *(const bf16x8*)&xs[wm * 32 + rt * 16 + l15][quad * 8];
    for (int nt = 0; nt < 8; nt++) {
      bf16x8 bfr = *(const bf16x8*)&ws[wn * 128 + nt * 16 + l15][quad * 8];
      for (int rt = 0; rt < 2; rt++)
        acc[rt][nt] = mfma16(af[rt], bfr, acc[rt][nt]);
    }
    __syncthreads();
  }

  // epilogue: bias, round, transpose via LDS
  for (int rt = 0; rt < 2; rt++)
    for (int nt = 0; nt < 8; nt++) {
      int c = wn * 128 + nt * 16 + l15;
      float bias = attnB[c];
      for (int r = 0; r < 4; r++) {
        float v = acc[rt][nt][r] + bias;
        int j = wm * 32 + rt * 16 + quad * 4 + r;
        St[c][j] = f2bf(v);
      }
    }
  __syncthreads();
  const int b = Mbase >> 10, jbase = Mbase & 1023;
  { // write shortcutT[b][c][jbase..jbase+64)
    unsigned short* dst = scT + ((size_t)b * 256 + t) * 1024 + jbase;
    for (int s = 0; s < 8; s++)
      *(uint4*)(dst + s * 8) = *(const uint4*)&St[t][s * 8];
  }
  { // Tinst
    float tp = 0.f;
    int j = t >> 2, cs = (t & 3) * 64;
    for (int c = 0; c < 64; c++)
      tp += bf2f(St[cs + c][j]) * thrW[cs + c];
    tp += __shfl_xor(tp, 1);
    tp += __shfl_xor(tp, 2);
    if ((t & 3) == 0) Tout[Mbase + j] = tp + thrB[0];
  }
}

// ---------------------------------------------------------------- k_scores
// grid 512 (32 batches x 16 row-blocks), block 256 = 4 waves, wave owns 16 rows.
__global__ __launch_bounds__(256) void k_scores(const unsigned short* __restrict__ embb,
                                                const float* __restrict__ sq,
                                                unsigned short* __restrict__ E,
                                                float* __restrict__ R) {
  const int t = threadIdx.x, lane = t & 63, wave = t >> 6;
  const int bid = blockIdx.x;
  const int b = bid >> 4, rb = (bid & 15) * 64;
  const int l15 = lane & 15, quad = lane >> 4;
  const unsigned short* eb = embb + (size_t)b * 1024 * 64;
  const int rowA = rb + wave * 16 + l15;
  bf16x8 a0 = *(const bf16x8*)(eb + (size_t)rowA * 64 + quad * 8);
  bf16x8 a1 = *(const bf16x8*)(eb + (size_t)rowA * 64 + 32 + quad * 8);
  const int rowC = rb + wave * 16 + quad * 4;
  float sqi[4]; int yi[4], xi[4];
  for (int r = 0; r < 4; r++) {
    sqi[r] = sq[b * 1024 + rowC + r];
    yi[r] = (rowC + r) >> 5; xi[r] = (rowC + r) & 31;
  }
  float rp[4] = {0.f, 0.f, 0.f, 0.f};
  for (int j0 = 0; j0 < 1024; j0 += 16) {
    const int jr = j0 + l15;
    bf16x8 b0 = *(const bf16x8*)(eb + (size_t)jr * 64 + quad * 8);
    bf16x8 b1 = *(const bf16x8*)(eb + (size_t)jr * 64 + 32 + quad * 8);
    f32x4 g = {0.f, 0.f, 0.f, 0.f};
    g = mfma16(a0, b0, g);
    g = mfma16(a1, b1, g);
    float sqj = sq[b * 1024 + jr];
    int yj = jr >> 5, xj = jr & 31;
    for (int r = 0; r < 4; r++) {
      float d2 = fmaxf(sqi[r] + sqj - 2.f * g[r], 0.f);
      int diff = iabs(yi[r] - yj) + iabs(xi[r] - xj);
      float m = (diff <= 32) ? (float)diff * (1.f / 32.f) : 0.f;
      float s = __expf(-d2) - 1.f + m;
      unsigned short h = f2bf(__expf(s));
      E[((size_t)(b * 1024 + rowC + r)) * 1024 + jr] = h;
      rp[r] += bf2f(h);   // R sums the rounded E (keeps softmax exactly normalized)
    }
  }
  for (int m = 8; m >= 1; m >>= 1)
    for (int r = 0; r < 4; r++)
      rp[r] += __shfl_xor(rp[r], m);
  if (l15 == 0)
    for (int r = 0; r < 4; r++)
      R[b * 1024 + rowC + r] = rp[r];
}

// ---------------------------------------------------------------- k_z
// grid 8192, block 256 = 4 waves; one wave per row.
__global__ __launch_bounds__(256) void k_z(const unsigned short* __restrict__ E,
                                           const float* __restrict__ R,
                                           const float* __restrict__ T,
                                           float* __restrict__ Z) {
  const int t = threadIdx.x, lane = t & 63, wave = t >> 6;
  const int row = blockIdx.x * 4 + wave;      // global row 0..32767
  const int b = row >> 10;
  const float invR = 1.f / R[row];
  const unsigned short* er = E + (size_t)row * 1024;
  const float* Tb = T + b * 1024;
  float z = 0.f;
  for (int it = 0; it < 4; it++) {
    int j = it * 256 + lane * 4;
    uint2 u = *(const uint2*)(er + j);
    float4 tv = *(const float4*)(Tb + j);
    z += __expf(fmaxf(fmaf(bf2f((unsigned short)(u.x & 0xffff)), invR, -tv.x), 0.f));
    z += __expf(fmaxf(fmaf(bf2f((unsigned short)(u.x >> 16)),    invR, -tv.y), 0.f));
    z += __expf(fmaxf(fmaf(bf2f((unsigned short)(u.y & 0xffff)), invR, -tv.z), 0.f));
    z += __expf(fmaxf(fmaf(bf2f((unsigned short)(u.y >> 16)),    invR, -tv.w), 0.f));
  }
  for (int m = 32; m >= 1; m >>= 1) z += __shfl_xor(z, m);
  if (lane == 0) Z[row] = z;
}

// ---------------------------------------------------------------- k_out
// grid 512 (32 b x 16 M-blocks), block 256. Tile 64 rows x 256 cols, waves 2x2.
__global__ __launch_bounds__(256) void k_out(const unsigned short* __restrict__ E,
                                             const float* __restrict__ R,
                                             const float* __restrict__ Z,
                                             const float* __restrict__ T,
                                             const unsigned short* __restrict__ scT,
                                             const float* __restrict__ x,
                                             float* __restrict__ out) {
  __shared__ unsigned short Bs[256][40];   // [c][k] tile of shortcutT
  const int t = threadIdx.x, lane = t & 63, wave = t >> 6;
  const int wm = wave >> 1, wn = wave & 1;
  const int l15 = lane & 15, quad = lane >> 4;
  const int bid = blockIdx.x;
  const int b = bid >> 4, rb = (bid & 15) * 64;
  int iA[2]; float invR_[2], invZ_[2];
  for (int rt = 0; rt < 2; rt++) {
    int i = rb + wm * 32 + rt * 16 + l15;
    iA[rt] = i;
    invR_[rt] = 1.f / R[b * 1024 + i];
    invZ_[rt] = 1.f / Z[b * 1024 + i];
  }
  const float* Tb = T + b * 1024;
  const unsigned short* Eb = E + (size_t)(b * 1024) * 1024;
  const unsigned short* sb = scT + (size_t)b * 256 * 1024;

  f32x4 acc[2][8] = {};
  for (int j0 = 0; j0 < 1024; j0 += 32) {
    { // stage Bs[c][k] = shortcutT[b][c][j0+k]; thread t = channel c
      const unsigned short* src = sb + (size_t)t * 1024 + j0;
      *(uint4*)&Bs[t][0]  = *(const uint4*)(src);
      *(uint4*)&Bs[t][8]  = *(const uint4*)(src + 8);
      *(uint4*)&Bs[t][16] = *(const uint4*)(src + 16);
      *(uint4*)&Bs[t][24] = *(const uint4*)(src + 24);
    }
    __syncthreads();
    // A fragments in registers: A[i][j0+quad*8+jj]
    union { float4 v[2]; float f[8]; } tv;
    tv.v[0] = *(const float4*)(Tb + j0 + quad * 8);
    tv.v[1] = *(const float4*)(Tb + j0 + quad * 8 + 4);
    bf16x8 af[2];
    for (int rt = 0; rt < 2; rt++) {
      union { uint4 v; unsigned short s[8]; } ev;
      ev.v = *(const uint4*)(Eb + (size_t)iA[rt] * 1024 + j0 + quad * 8);
      union { bf16x8 v; unsigned short s[8]; } fr;
      for (int jj = 0; jj < 8; jj++) {
        float u = fmaxf(fmaf(bf2f(ev.s[jj]), invR_[rt], -tv.f[jj]), 0.f);
        fr.s[jj] = f2bf(__expf(u) * invZ_[rt]);
      }
      af[rt] = fr.v;
    }
    for (int nt = 0; nt < 8; nt++) {
      bf16x8 bfr = *(const bf16x8*)&Bs[wn * 128 + nt * 16 + l15][quad * 8];
      for (int rt = 0; rt < 2; rt++)
        acc[rt][nt] = mfma16(af[rt], bfr, acc[rt][nt]);
    }
    __syncthreads();
  }
  for (int rt = 0; rt < 2; rt++)
    for (int nt = 0; nt < 8; nt++) {
      int c = wn * 128 + nt * 16 + l15;
      for (int r = 0; r < 4; r++) {
        int i = rb + wm * 32 + rt * 16 + quad * 4 + r;
        size_t idx = ((size_t)(b * 1024 + i)) * 256 + c;
        out[idx] = x[idx] + acc[rt][nt][r];
      }
    }
}

// ---------------------------------------------------------------- launch
extern "C" void kernel_launch(void* const* d_in, const int* in_sizes, int n_in,
                              void* d_out, int out_size, void* d_ws, size_t ws_size,
                              hipStream_t stream) {
  const float* x     = (const float*)d_in[0];
  const float* embW  = (const float*)d_in[1];
  const float* embB  = (const float*)d_in[2];
  const float* attnW = (const float*)d_in[3];
  const float* attnB = (const float*)d_in[4];
  const float* thrW  = (const float*)d_in[5];
  const float* thrB  = (const float*)d_in[6];
  float* out = (float*)d_out;

  char* ws = (char*)d_ws;
  // layout: embb 4MB | scT 16MB | E 64MB | sq 128K | T 128K | R 128K | Z 128K
  unsigned short* embb = (unsigned short*)(ws);
  unsigned short* scT  = (unsigned short*)(ws + (4ull << 20));
  unsigned short* E    = (unsigned short*)(ws + (20ull << 20));
  float* sq = (float*)(ws + (84ull << 20));
  float* T  = (float*)(ws + (84ull << 20) + (128ull << 10));
  float* R  = (float*)(ws + (84ull << 20) + (256ull << 10));
  float* Z  = (float*)(ws + (84ull << 20) + (384ull << 10));

  k_emb<<<512, 256, 0, stream>>>(x, embW, embB, embb, sq);
  k_shortcut<<<512, 256, 0, stream>>>(x, attnW, attnB, thrW, thrB, scT, T);
  k_scores<<<512, 256, 0, stream>>>(embb, sq, E, R);
  k_z<<<8192, 256, 0, stream>>>(E, R, T, Z);
  k_out<<<512, 256, 0, stream>>>(E, R, Z, T, scT, x, out);
}